// Round 8
// baseline (495.940 us; speedup 1.0000x reference)
//
#include <hip/hip_runtime.h>

// (N,C,H,W) = (4,64,96,96), K=3, dilations {1,3,5}. Single fused MFMA kernel.
typedef _Float16 f16;
typedef _Float16 f16x8 __attribute__((ext_vector_type(8)));
typedef float f32x4 __attribute__((ext_vector_type(4)));

#define H 96
#define W 96
#define HWv (H * W)
#define PREC 9604              // padded records per image (98x98)
// ws layout: xcatp (f16, padded 98x98, 128B/record) | gwp | fwp
#define GWP_OFF 4917248        // = 4*9604*128
#define FWP_OFF 5138432        // = GWP_OFF + 216*1024

// ---------------------------------------------------------------------------
// K0: pack gen_w -> gwp A-frags, fuse_w -> fwp A-frags (lane&15 = M row,
// k = (lane>>4)*8+j), transpose x -> xcatp f16 (padded, borders zeroed).
// Grid 2481: [0,128) weight pack | [128,2432) x transpose | [2432,2481) borders
// ---------------------------------------------------------------------------
__global__ __launch_bounds__(256) void prep_kernel(
    const float* __restrict__ gen_w, const float* __restrict__ fuse_w,
    const float* __restrict__ x, unsigned char* __restrict__ ws)
{
    const int bid = blockIdx.x, tid = threadIdx.x;
    if (bid < 128) {
        const int gid = bid * 256 + tid;
        const int lane = gid & 63;
        if (gid < 18432) {                      // fwp: frag (cot,tap,s)
            const int rest = gid >> 6;
            const int s = rest & 7;
            const int rest2 = rest >> 3;
            const int tap = rest2 % 9, cot = rest2 / 9;
            const int co = cot * 16 + (lane & 15);
            const int ci0 = s * 32 + (lane >> 4) * 8;
            f16x8 v;
#pragma unroll
            for (int j = 0; j < 8; ++j)
                v[j] = (f16)fuse_w[(co * 256 + ci0 + j) * 9 + tap];
            reinterpret_cast<f16x8*>(ws + FWP_OFF)[rest * 64 + lane] = v;
        } else if (gid < 32256) {               // gwp: frag (T,s)
            const int fid = gid - 18432;
            const int lane2 = fid & 63;
            const int rest = fid >> 6;
            const int T = rest >> 1, s = rest & 1;
            const int o = T * 16 + (lane2 & 15);
            const int cc0 = s * 32 + (lane2 >> 4) * 8;
            f16x8 v;
#pragma unroll
            for (int j = 0; j < 8; ++j)
                v[j] = (f16)gen_w[o * 64 + cc0 + j];
            reinterpret_cast<f16x8*>(ws + GWP_OFF)[rest * 64 + lane2] = v;
        }
    } else if (bid < 2432) {
        // x transpose: 1x16 px strip x 64 ch -> one 128B record per px
        __shared__ __align__(16) unsigned char xls[2048];
        const int tb = bid - 128;
        const int n = tb / 576, rem = tb % 576;
        const int h0 = rem / 6, w0 = (rem % 6) * 16;
        const int scc = tid >> 2, sp4 = (tid & 3) * 4;
        const f32x4 xv4 = *reinterpret_cast<const f32x4*>(
            x + (size_t)(n * 64 + scc) * HWv + h0 * W + w0 + sp4);
#pragma unroll
        for (int k = 0; k < 4; ++k) {
            const int p = sp4 + k;
            *reinterpret_cast<f16*>(xls + ((p * 128 + scc * 2) ^ ((p & 7) << 4)))
                = (f16)xv4[k];
        }
        __syncthreads();
        if (tid < 128) {
            const int pxf = tid >> 3, c16 = tid & 7;
            const int4 v = *reinterpret_cast<const int4*>(
                xls + ((pxf * 128 + c16 * 16) ^ ((pxf & 7) << 4)));
            const size_t rec = (size_t)n * PREC + (size_t)(h0 + 1) * 98 + (w0 + pxf + 1);
            *reinterpret_cast<int4*>(ws + rec * 128 + c16 * 16) = v;
        }
    } else {
        // zero borders: 4 images * 388 records * 8 chunks of 16B
        const int idx = (bid - 2432) * 256 + tid;
        if (idx < 12416) {
            const int rec = idx >> 3, chunk = idx & 7;
            const int n = rec / 388, rr = rec % 388;
            int r, c;
            if (rr < 196) { r = (rr < 98) ? 0 : 97; c = rr % 98; }
            else { const int k2 = rr - 196; c = (k2 < 96) ? 0 : 97; r = 1 + (k2 % 96); }
            const int4 z{0, 0, 0, 0};
            *reinterpret_cast<int4*>(
                ws + ((size_t)n * PREC + (size_t)r * 98 + c) * 128 + chunk * 16) = z;
        }
    }
}

// ---------------------------------------------------------------------------
// Mega kernel: per 4x16 output tile (grid 576, 256 thr / 4 waves):
//  1. stage y halo (6x18=108 px, 64 ch) -> LDS f16 swizzled
//  2. cache gen B-frags (7 N-tiles x 2) in registers
//  3. for g in 0..11: gen-MFMA 16 ch (144 rows) -> klds; barrier;
//     dynconv 16 ch x 108 px (x from global) -> dyncat LDS; barrier
//  4. stage xcatp halo slice (108 px x 64 ci) into klds region
//  5. fuse conv: 8 K-slices x (9 taps x 4 N-tiles) MFMA from LDS; store out
// LDS 76.5 KB -> 2 blocks/CU. No HBM intermediates.
// ---------------------------------------------------------------------------
__global__ __launch_bounds__(256, 2) void mega_kernel(
    const float* __restrict__ x, const float* __restrict__ y,
    const float* __restrict__ gen_b, const unsigned char* __restrict__ ws,
    const float* __restrict__ fb, float* __restrict__ out)
{
    // [0,36864) klds [144][128B] swz   (yls/xcat [<=112][128B] overlay)
    // [36864,78336) dyncat [108][384B] swz
    __shared__ __align__(16) unsigned char smem[78336];
    const int tid = threadIdx.x, lane = tid & 63, wv = tid >> 6;
    const int q4 = lane >> 4;
    const int bid = blockIdx.x;
    const int n = bid / 144, tile = bid % 144;
    const int h0 = (tile / 6) * 4, w0 = (tile % 6) * 16;
    unsigned char* dyncat = smem + 36864;

    // ---- phase 1: y halo stage (108 px x 64 ch), clamp OOB reads ----
#pragma unroll
    for (int it = 0; it < 27; ++it) {
        const int e = tid + it * 256;           // < 6912
        const int c = e / 108, px = e - c * 108;
        const int r = px / 18, cc = px - r * 18;
        int hh = h0 - 1 + r, ww = w0 - 1 + cc;
        hh = hh < 0 ? 0 : (hh > 95 ? 95 : hh);
        ww = ww < 0 ? 0 : (ww > 95 ? 95 : ww);
        const float v = y[(size_t)(n * 64 + c) * HWv + hh * W + ww];
        *reinterpret_cast<f16*>(smem + ((px * 128 + c * 2) ^ ((px & 7) << 4))) = (f16)v;
    }
    if (tid < 32) {   // zero junk rows 108..111 (feed nb=6 MFMA junk cols)
        const int px = 108 + (tid >> 3), chunk = tid & 7;
        const int4 z{0, 0, 0, 0};
        *reinterpret_cast<int4*>(smem + ((px * 128 + chunk * 16) ^ ((px & 7) << 4))) = z;
    }
    __syncthreads();

    // ---- phase 2: gen B-frags -> registers (7 N-tiles x 2 K-halves) ----
    f16x8 Bf[7][2];
#pragma unroll
    for (int nb = 0; nb < 7; ++nb)
#pragma unroll
        for (int s = 0; s < 2; ++s) {
            const int px = nb * 16 + (lane & 15);
            Bf[nb][s] = *reinterpret_cast<const f16x8*>(
                smem + ((px * 128 + s * 64 + q4 * 16) ^ ((px & 7) << 4)));
        }
    __syncthreads();   // yls region now reusable as klds

    const f16x8* gwp = reinterpret_cast<const f16x8*>(ws + GWP_OFF);

    // ---- phase 3: 12 groups of 16 channels ----
    for (int g = 0; g < 12; ++g) {
        // gen-MFMA: 63 (t,nb) units split {16,16,16,15} across waves
        {
            const int ustart = wv * 16;
            const int uend = (ustart + 16 < 63) ? ustart + 16 : 63;
            int u = ustart;
            while (u < uend) {
                const int t = u / 7;
                const int T = g * 9 + t;
                const f16x8 A0 = gwp[(T * 2 + 0) * 64 + lane];
                const f16x8 A1 = gwp[(T * 2 + 1) * 64 + lane];
                const f32x4 gb4 = *reinterpret_cast<const f32x4*>(gen_b + T * 16 + q4 * 4);
                const int nbe = (uend - t * 7 < 7) ? uend - t * 7 : 7;
                for (int nb = u - t * 7; nb < nbe; ++nb, ++u) {
                    f32x4 a = {0.f, 0.f, 0.f, 0.f};
                    a = __builtin_amdgcn_mfma_f32_16x16x32_f16(A0, Bf[nb][0], a, 0, 0, 0);
                    a = __builtin_amdgcn_mfma_f32_16x16x32_f16(A1, Bf[nb][1], a, 0, 0, 0);
                    const int px = nb * 16 + (lane & 15);
#pragma unroll
                    for (int r = 0; r < 4; ++r) {
                        const int o = t * 16 + q4 * 4 + r;
                        *reinterpret_cast<f16*>(
                            smem + ((o * 256 + px * 2) ^ ((o & 7) << 4)))
                            = (f16)(a[r] + gb4[r]);
                    }
                }
            }
        }
        __syncthreads();
        // dynconv: 16 ch x 108 px, results -> dyncat (0 for out-of-image px)
        {
            const int chl = tid >> 4, pxt = tid & 15;
            const int ch = g * 16 + chl;
            const int bbr = ch >> 6, c = ch & 63, d = 2 * bbr + 1;
            const float* xc = x + (size_t)(n * 64 + c) * HWv;
#pragma unroll
            for (int k = 0; k < 7; ++k) {
                const int px = pxt + k * 16;
                if (px < 108) {
                    const int r = px / 18, cc = px - r * 18;
                    const int hh = h0 - 1 + r, ww = w0 - 1 + cc;
                    f16 res = (f16)0.f;
                    if (hh >= 0 && hh < H && ww >= 0 && ww < W) {
                        float acc = 0.f;
#pragma unroll
                        for (int tap = 0; tap < 9; ++tap) {
                            const int o = chl * 9 + tap;
                            const float kv = (float)*reinterpret_cast<const f16*>(
                                smem + ((o * 256 + px * 2) ^ ((o & 7) << 4)));
                            const int h2 = hh + (tap / 3 - 1) * d;
                            const int w2 = ww + (tap % 3 - 1) * d;
                            if (h2 >= 0 && h2 < H && w2 >= 0 && w2 < W)
                                acc = fmaf(kv, xc[h2 * W + w2], acc);
                        }
                        res = (f16)acc;
                    }
                    *reinterpret_cast<f16*>(
                        dyncat + ((px * 384 + ch * 2) ^ ((px & 7) << 4))) = res;
                }
            }
        }
        __syncthreads();
    }

    // ---- phase 4: stage xcatp halo (108 px x 64 ci) into klds region ----
#pragma unroll
    for (int it = 0; it < 4; ++it) {
        const int e = tid + it * 256;           // 864 chunks of 16B
        if (e < 864) {
            const int hpx = e >> 3, chunk = e & 7;
            const int r = hpx / 18, cc = hpx - r * 18;
            const size_t rec = (size_t)n * PREC + (size_t)(h0 + r) * 98 + (w0 + cc);
            const int4 v = *reinterpret_cast<const int4*>(ws + rec * 128 + chunk * 16);
            *reinterpret_cast<int4*>(
                smem + ((hpx * 128 + chunk * 16) ^ ((hpx & 7) << 4))) = v;
        }
    }
    __syncthreads();

    // ---- phase 5: fuse conv, wave = 16-co tile, acc over 4 N-tiles ----
    f32x4 acc[4];
#pragma unroll
    for (int i = 0; i < 4; ++i) acc[i] = {0.f, 0.f, 0.f, 0.f};

    const f16x8* fwp = reinterpret_cast<const f16x8*>(ws + FWP_OFF);
    for (int s = 0; s < 8; ++s) {
        // B-frags: 6 halo rows x 3 col-shifts from LDS
        f16x8 B[6][3];
#pragma unroll
        for (int r = 0; r < 6; ++r)
#pragma unroll
            for (int dc = 0; dc < 3; ++dc) {
                const int px = r * 18 + dc + (lane & 15);
                if (s < 2) {
                    B[r][dc] = *reinterpret_cast<const f16x8*>(
                        smem + ((px * 128 + s * 64 + q4 * 16) ^ ((px & 7) << 4)));
                } else {
                    B[r][dc] = *reinterpret_cast<const f16x8*>(
                        dyncat + ((px * 384 + (s - 2) * 64 + q4 * 16) ^ ((px & 7) << 4)));
                }
            }
#pragma unroll
        for (int tap = 0; tap < 9; ++tap) {
            const int dr = tap / 3, dc = tap % 3;
            const f16x8 Af = fwp[((wv * 9 + tap) * 8 + s) * 64 + lane];
#pragma unroll
            for (int nb = 0; nb < 4; ++nb)
                acc[nb] = __builtin_amdgcn_mfma_f32_16x16x32_f16(
                    Af, B[nb + dr][dc], acc[nb], 0, 0, 0);
        }
    }

    // ---- bias + store ----
    const int co0 = wv * 16 + q4 * 4;
    const f32x4 fb4 = *reinterpret_cast<const f32x4*>(fb + co0);
#pragma unroll
    for (int nb = 0; nb < 4; ++nb) {
        const int hh = h0 + nb, ww = w0 + (lane & 15);
#pragma unroll
        for (int r = 0; r < 4; ++r)
            out[(size_t)(n * 64 + co0 + r) * HWv + hh * W + ww] = acc[nb][r] + fb4[r];
    }
}

// ---------------------------------------------------------------------------
extern "C" void kernel_launch(void* const* d_in, const int* in_sizes, int n_in,
                              void* d_out, int out_size, void* d_ws, size_t ws_size,
                              hipStream_t stream) {
    const float* x      = (const float*)d_in[0];
    const float* y      = (const float*)d_in[1];
    const float* gen_w  = (const float*)d_in[2];
    const float* gen_b  = (const float*)d_in[3];
    const float* fuse_w = (const float*)d_in[4];
    const float* fuse_b = (const float*)d_in[5];
    unsigned char* ws = (unsigned char*)d_ws;

    prep_kernel<<<2481, 256, 0, stream>>>(gen_w, fuse_w, x, ws);
    mega_kernel<<<576, 256, 0, stream>>>(x, y, gen_b, ws, fuse_b, (float*)d_out);
}

// Round 9
// 176.971 us; speedup vs baseline: 2.8024x; 2.8024x over previous
//
#include <hip/hip_runtime.h>

// (N,C,H,W) = (4,64,96,96), K=3, dilations {1,3,5}. Full-MFMA fp16.
typedef _Float16 f16;
typedef _Float16 f16x8 __attribute__((ext_vector_type(8)));
typedef _Float16 f16x4 __attribute__((ext_vector_type(4)));
typedef float f32x4 __attribute__((ext_vector_type(4)));

#define H 96
#define W 96
#define HWv (H * W)
#define PREC 9604              // padded records per image (98*98)
// ws layout: catp (f16 NHWC, padded 98x98, 512B/record) | gwp | fwp
#define GWP_OFF  19668992      // = 4*9604*512
#define FWP_OFF  19890176      // = GWP_OFF + 216*1024

__device__ __forceinline__ size_t prec_rec(int n, int h, int w) {
    return (size_t)n * PREC + (size_t)(h + 1) * 98 + (w + 1);
}

// ---------------------------------------------------------------------------
// K0: pack gen_w -> gwp A-frags, fuse_w -> fwp A-frags, zero catp borders.
// A-frag: lane&15 = M row, k = (lane>>4)*8+j.   (unchanged from R4-R7)
// ---------------------------------------------------------------------------
__global__ __launch_bounds__(256) void prep_kernel(
    const float* __restrict__ gen_w, const float* __restrict__ fuse_w,
    unsigned char* __restrict__ ws)
{
    const int bid = blockIdx.x, tid = threadIdx.x;
    if (bid < 128) {
        const int gid = bid * 256 + tid;
        const int lane = gid & 63;
        if (gid < 18432) {                      // fwp: frag (cot,tap,s)
            const int rest = gid >> 6;
            const int s = rest & 7;
            const int rest2 = rest >> 3;
            const int tap = rest2 % 9, cot = rest2 / 9;
            const int co = cot * 16 + (lane & 15);
            const int ci0 = s * 32 + (lane >> 4) * 8;
            f16x8 v;
#pragma unroll
            for (int j = 0; j < 8; ++j)
                v[j] = (f16)fuse_w[(co * 256 + ci0 + j) * 9 + tap];
            reinterpret_cast<f16x8*>(ws + FWP_OFF)[rest * 64 + lane] = v;
        } else if (gid < 32256) {               // gwp: frag (T,s)
            const int fid = gid - 18432;
            const int lane2 = fid & 63;
            const int rest = fid >> 6;
            const int T = rest >> 1, s = rest & 1;
            const int o = T * 16 + (lane2 & 15);
            const int cc0 = s * 32 + (lane2 >> 4) * 8;
            f16x8 v;
#pragma unroll
            for (int j = 0; j < 8; ++j)
                v[j] = (f16)gen_w[o * 64 + cc0 + j];
            reinterpret_cast<f16x8*>(ws + GWP_OFF)[rest * 64 + lane2] = v;
        }
    } else {
        const int idx0 = (bid - 128) * 256 + tid;
        for (int k = idx0; k < 49664; k += 32768) {
            const int rec = k >> 5, chunk = k & 31;
            const int n = rec / 388, rr = rec % 388;
            int r, c;
            if (rr < 196) { r = (rr < 98) ? 0 : 97; c = rr % 98; }
            else { const int k2 = rr - 196; c = (k2 < 96) ? 0 : 97; r = 1 + (k2 % 96); }
            const int4 z{0, 0, 0, 0};
            *reinterpret_cast<int4*>(
                ws + ((size_t)n * PREC + (size_t)r * 98 + c) * 512 + chunk * 16) = z;
        }
    }
}

// ---------------------------------------------------------------------------
// K1: gen GEMM (MFMA f16) + dynamic depthwise conv. Grid 2304 (1x16 tiles),
// 256 thr / 4 waves, 50176 B LDS -> 3 blk/CU. Key change vs R7: the x-halo
// (7 rows x 64 ch x 28 cols, f16) is staged ONCE per block with coalesced
// f32x2 loads; the dynconv epilogue reads LDS instead of issuing ~5M
// scattered per-channel-plane global loads. Cat flushes are full-line:
// per qi-round, all 4 waves produce 64 channels -> 128B contiguous/record.
// XCD-contiguous bid swizzle for halo L2 sharing.
// ---------------------------------------------------------------------------
__global__ __launch_bounds__(256, 3) void gen_dyn_kernel(
    const float* __restrict__ x, const float* __restrict__ y,
    const float* __restrict__ gen_b, unsigned char* __restrict__ ws)
{
    // [0,2048) yls (stage) -> cs [16px][64ch] f16 (epilogue)
    // [2048,25088) klds: 4 waves x [144][20] f16
    // [25088,50176) xhalo [7 rows][64 ch][28 cols] f16
    __shared__ __align__(16) unsigned char smem[50176];
    const int tid = threadIdx.x, lane = tid & 63, wv = tid >> 6;
    const int q4 = lane >> 4, px = lane & 15;
    const int bid0 = blockIdx.x;
    const int bid = (bid0 & 7) * 288 + (bid0 >> 3);   // XCD-contiguous
    const int n = bid / 576, rem = bid % 576;
    const int h0 = rem / 6, w0 = (rem % 6) * 16;

    unsigned char* yls = smem;
    f16* cs    = reinterpret_cast<f16*>(smem);                   // [16][64]
    f16* klds  = reinterpret_cast<f16*>(smem + 2048 + wv * 5760);// [144][20]
    f16* xhalo = reinterpret_cast<f16*>(smem + 25088);           // [7][64][28]

    // ---- stage y tile (16px x 64ch) ----
    {
        const int scc = tid >> 2, sp4 = (tid & 3) * 4;
        const f32x4 yv4 = *reinterpret_cast<const f32x4*>(
            y + (size_t)(n * 64 + scc) * HWv + h0 * W + w0 + sp4);
#pragma unroll
        for (int k = 0; k < 4; ++k) {
            const int p = sp4 + k;
            *reinterpret_cast<f16*>(yls + ((p * 128 + scc * 2) ^ ((p & 7) << 4)))
                = (f16)yv4[k];
        }
    }
    // ---- stage xhalo: rows {-5,-3,-1,0,1,3,5}, cols w0-6..w0+21 ----
    for (int it = 0; it < 25; ++it) {
        const int e = tid + it * 256;
        if (e < 6272) {                         // 7*64*14 f32x2 chunks
            const int j = e / 896;
            const int r2 = e - j * 896;
            const int ch = r2 / 14, p = r2 - ch * 14;
            const int offj = (j < 3) ? 2 * j - 5 : ((j > 3) ? 2 * j - 7 : 0);
            int hh = h0 + offj; hh = hh < 0 ? 0 : (hh > 95 ? 95 : hh);
            int wb = w0 - 6 + p * 2; wb = wb < 0 ? 0 : (wb > 94 ? 94 : wb);
            const float2 v = *reinterpret_cast<const float2*>(
                x + (size_t)(n * 64 + ch) * HWv + hh * W + wb);
            union { f16 h[2]; unsigned int u; } pk;
            pk.h[0] = (f16)v.x; pk.h[1] = (f16)v.y;
            *reinterpret_cast<unsigned int*>(&xhalo[(j * 64 + ch) * 28 + p * 2]) = pk.u;
        }
    }
    __syncthreads();

    // ---- x passthrough: record bytes [0,128) from xhalo row 3 ----
    if (tid < 128) {
        const int pxr = tid >> 3, c8 = tid & 7;
        union { f16 h[8]; int4 v; } pk;
#pragma unroll
        for (int jj = 0; jj < 8; ++jj)
            pk.h[jj] = xhalo[(3 * 64 + c8 * 8 + jj) * 28 + pxr + 6];
        *reinterpret_cast<int4*>(ws + prec_rec(n, h0, w0 + pxr) * 512 + c8 * 16) = pk.v;
    }
    // ---- B fragments (y) -> registers ----
    f16x8 Bf[2];
#pragma unroll
    for (int s = 0; s < 2; ++s)
        Bf[s] = *reinterpret_cast<const f16x8*>(
            yls + ((px * 128 + s * 64 + q4 * 16) ^ ((px & 7) << 4)));
    __syncthreads();   // yls region becomes cs

    const f16x8* gwp = reinterpret_cast<const f16x8*>(ws + GWP_OFF);
    const bool interior = (h0 >= 5) && (h0 <= 90) && (w0 >= 16) && (w0 <= 64);
    const int chl = lane >> 2, wu = lane & 3;

    for (int qi = 0; qi < 3; ++qi) {
        const int q = qi * 4 + wv;              // chunk: channels [q*16,q*16+16)
        // --- MFMA: 9 T-tiles -> klds (per-wave region, stride 20) ---
#pragma unroll 3
        for (int t = 0; t < 9; ++t) {
            const int T = q * 9 + t;
            const f16x8 A0 = gwp[(T * 2 + 0) * 64 + lane];
            const f16x8 A1 = gwp[(T * 2 + 1) * 64 + lane];
            const f32x4 gb4 = *reinterpret_cast<const f32x4*>(gen_b + T * 16 + q4 * 4);
            f32x4 a = {0.f, 0.f, 0.f, 0.f};
            a = __builtin_amdgcn_mfma_f32_16x16x32_f16(A0, Bf[0], a, 0, 0, 0);
            a = __builtin_amdgcn_mfma_f32_16x16x32_f16(A1, Bf[1], a, 0, 0, 0);
#pragma unroll
            for (int r = 0; r < 4; ++r)
                klds[(t * 16 + q4 * 4 + r) * 20 + px] = (f16)(a[r] + gb4[r]);
        }
        asm volatile("s_waitcnt lgkmcnt(0)" ::: "memory");
        __builtin_amdgcn_sched_barrier(0);
        // --- dynconv epilogue: all reads from LDS ---
        {
            const int ch = q * 16 + chl;
            const int bb = ch >> 6, c = ch & 63, d = 2 * bb + 1;
            f32x4 racc = {0.f, 0.f, 0.f, 0.f};
            if (interior) {
#pragma unroll
                for (int tap = 0; tap < 9; ++tap) {
                    const f16x4 k4 = *reinterpret_cast<const f16x4*>(
                        &klds[(chl * 9 + tap) * 20 + wu * 4]);
                    const int ti = tap / 3 - 1, tj = tap % 3 - 1;
                    const int j = 3 + ti * (bb + 1);
                    const f16* xr = &xhalo[(j * 64 + c) * 28 + wu * 4 + tj * d + 6];
                    racc[0] = fmaf((float)k4[0], (float)xr[0], racc[0]);
                    racc[1] = fmaf((float)k4[1], (float)xr[1], racc[1]);
                    racc[2] = fmaf((float)k4[2], (float)xr[2], racc[2]);
                    racc[3] = fmaf((float)k4[3], (float)xr[3], racc[3]);
                }
            } else {
#pragma unroll
                for (int tap = 0; tap < 9; ++tap) {
                    const f16x4 k4 = *reinterpret_cast<const f16x4*>(
                        &klds[(chl * 9 + tap) * 20 + wu * 4]);
                    const int ti = tap / 3 - 1, tj = tap % 3 - 1;
                    const int j = 3 + ti * (bb + 1);
                    const int hh = h0 + ti * d;
                    if (hh >= 0 && hh < H) {
                        const f16* xr = &xhalo[(j * 64 + c) * 28 + wu * 4 + tj * d + 6];
                        const int wwb = w0 + wu * 4 + tj * d;
#pragma unroll
                        for (int kk = 0; kk < 4; ++kk) {
                            const int wk = wwb + kk;
                            if (wk >= 0 && wk < W)
                                racc[kk] = fmaf((float)k4[kk], (float)xr[kk], racc[kk]);
                        }
                    }
                }
            }
#pragma unroll
            for (int kk = 0; kk < 4; ++kk)
                cs[(wu * 4 + kk) * 64 + wv * 16 + chl] = (f16)racc[kk];
        }
        __syncthreads();
        // --- flush: 16 records x 128B contiguous (full 64B lines) ---
        if (tid < 128) {
            const int pxr = tid >> 3, c8 = tid & 7;
            const int4 v = *reinterpret_cast<const int4*>(&cs[pxr * 64 + c8 * 8]);
            *reinterpret_cast<int4*>(
                ws + prec_rec(n, h0, w0 + pxr) * 512 + 128 + qi * 128 + c8 * 16) = v;
        }
        __syncthreads();
    }
}

// ---------------------------------------------------------------------------
// K2: fuse conv 3x3 Cin=256 Cout=64, MFMA implicit GEMM, s-sliced staging.
// Grid 576 (n, 4x16 tile), 256 thr / 4 waves = (pb-pair, co-half).
// Double-buffered 32-ci slice staging, reg prefetch (T14). Unchanged from R7
// except XCD-contiguous bid swizzle.
// ---------------------------------------------------------------------------
__global__ __launch_bounds__(256, 3) void fuse_mfma_kernel(
    const unsigned char* __restrict__ ws, const float* __restrict__ fb,
    float* __restrict__ out)
{
    __shared__ __align__(16) unsigned char smem[13824];  // 2 x [108 hpx][64B]
    const int tid = threadIdx.x, lane = tid & 63, wv = tid >> 6;
    const int q4 = lane >> 4;
    const int bid0 = blockIdx.x;
    const int bid = (bid0 & 7) * 72 + (bid0 >> 3);       // XCD-contiguous
    const int n = bid / 144, tile = bid % 144;
    const int h0 = (tile / 6) * 4, w0 = (tile % 6) * 16;
    const int pbp = wv & 1, coh = wv >> 1;

    const int e0 = tid, e1 = tid + 256;
    const int hpx0 = e0 >> 2, cc0 = e0 & 3;
    const int hpx1 = e1 >> 2, cc1 = e1 & 3;
    const size_t rb0 = prec_rec(n, h0 - 1 + hpx0 / 18, w0 - 1 + hpx0 % 18) * 512;
    const size_t rb1 = prec_rec(n, h0 - 1 + hpx1 / 18, w0 - 1 + hpx1 % 18) * 512;
    const int dso0 = hpx0 * 64 + ((cc0 * 16) ^ (((hpx0 >> 1) & 3) << 4));
    const int dso1 = hpx1 * 64 + ((cc1 * 16) ^ (((hpx1 >> 1) & 3) << 4));

    *reinterpret_cast<int4*>(smem + dso0) =
        *reinterpret_cast<const int4*>(ws + rb0 + cc0 * 16);
    if (tid < 176)
        *reinterpret_cast<int4*>(smem + dso1) =
            *reinterpret_cast<const int4*>(ws + rb1 + cc1 * 16);
    __syncthreads();

    f32x4 acc[2][2];
#pragma unroll
    for (int i = 0; i < 2; ++i)
#pragma unroll
        for (int j = 0; j < 2; ++j) acc[i][j] = {0.f, 0.f, 0.f, 0.f};

    const f16x8* fwp = reinterpret_cast<const f16x8*>(ws + FWP_OFF);

    for (int s = 0; s < 8; ++s) {
        unsigned char* buf  = smem + (s & 1) * 6912;
        unsigned char* nbuf = smem + ((s & 1) ^ 1) * 6912;
        int4 pf0{0,0,0,0}, pf1{0,0,0,0};
        if (s < 7) {
            pf0 = *reinterpret_cast<const int4*>(ws + rb0 + (s + 1) * 64 + cc0 * 16);
            if (tid < 176)
                pf1 = *reinterpret_cast<const int4*>(ws + rb1 + (s + 1) * 64 + cc1 * 16);
        }
        f16x8 B[4][3];
#pragma unroll
        for (int r = 0; r < 4; ++r)
#pragma unroll
            for (int cd = 0; cd < 3; ++cd) {
                const int hpx = (pbp * 2 + r) * 18 + (lane & 15) + cd;
                B[r][cd] = *reinterpret_cast<const f16x8*>(
                    buf + hpx * 64 + ((q4 * 16) ^ (((hpx >> 1) & 3) << 4)));
            }
#pragma unroll
        for (int tap = 0; tap < 9; ++tap) {
            const int rb = tap / 3, cd = tap % 3;
            f16x8 Af[2];
#pragma unroll
            for (int j = 0; j < 2; ++j)
                Af[j] = fwp[(((coh * 2 + j) * 9 + tap) * 8 + s) * 64 + lane];
#pragma unroll
            for (int i = 0; i < 2; ++i)
#pragma unroll
                for (int j = 0; j < 2; ++j)
                    acc[i][j] = __builtin_amdgcn_mfma_f32_16x16x32_f16(
                        Af[j], B[i + rb][cd], acc[i][j], 0, 0, 0);
        }
        if (s < 7) {
            *reinterpret_cast<int4*>(nbuf + dso0) = pf0;
            if (tid < 176)
                *reinterpret_cast<int4*>(nbuf + dso1) = pf1;
        }
        __syncthreads();
    }

#pragma unroll
    for (int i = 0; i < 2; ++i) {
        const int hh = h0 + pbp * 2 + i, ww = w0 + (lane & 15);
#pragma unroll
        for (int j = 0; j < 2; ++j) {
            const int co0 = (coh * 2 + j) * 16 + q4 * 4;
            const f32x4 fb4 = *reinterpret_cast<const f32x4*>(fb + co0);
#pragma unroll
            for (int r = 0; r < 4; ++r)
                out[(size_t)(n * 64 + co0 + r) * HWv + hh * W + ww]
                    = acc[i][j][r] + fb4[r];
        }
    }
}

// ---------------------------------------------------------------------------
extern "C" void kernel_launch(void* const* d_in, const int* in_sizes, int n_in,
                              void* d_out, int out_size, void* d_ws, size_t ws_size,
                              hipStream_t stream) {
    const float* x      = (const float*)d_in[0];
    const float* y      = (const float*)d_in[1];
    const float* gen_w  = (const float*)d_in[2];
    const float* gen_b  = (const float*)d_in[3];
    const float* fuse_w = (const float*)d_in[4];
    const float* fuse_b = (const float*)d_in[5];
    unsigned char* ws = (unsigned char*)d_ws;

    prep_kernel<<<256, 256, 0, stream>>>(gen_w, fuse_w, ws);
    gen_dyn_kernel<<<2304, 256, 0, stream>>>(x, y, gen_b, ws);
    fuse_mfma_kernel<<<576, 256, 0, stream>>>(ws, fuse_b, (float*)d_out);
}